// Round 8
// baseline (164.319 us; speedup 1.0000x reference)
//
#include <hip/hip_runtime.h>
#include <math.h>

#define DIM_ 1024
#define B_ 4
#define S_ 512
#define H_ 16
#define HD_ 64
#define SCORE_SCALE_ 0.07216878364870323f

typedef __attribute__((ext_vector_type(8))) short bf16x8;
typedef __attribute__((ext_vector_type(4))) float f32x4;

__device__ __forceinline__ unsigned short f2bf(float f) {
    unsigned int u = __float_as_uint(f);
    u = u + 0x7fffu + ((u >> 16) & 1u);   // RNE (no NaN in data)
    return (unsigned short)(u >> 16);
}
__device__ __forceinline__ float bfs(unsigned short s) { return __uint_as_float(((unsigned int)s) << 16); }

__device__ __forceinline__ void gload16(const void* g, void* l) {
    __builtin_amdgcn_global_load_lds((const __attribute__((address_space(1))) void*)g,
                                     (__attribute__((address_space(3))) void*)l, 16, 0, 0);
}

// ---------------------------------------------------------------------------
// fp32 -> bf16 for x (first 524288 float4) and rel (next 262144), one launch
// ---------------------------------------------------------------------------
__global__ __launch_bounds__(256) void cvt2_bf16(const float* __restrict__ x,
                                                 const float* __restrict__ rel,
                                                 unsigned short* __restrict__ dst) {
    const int i = blockIdx.x * 256 + threadIdx.x;        // 0 .. 786431
    const float* src = (i < 524288) ? &x[(size_t)i * 4]
                                    : &rel[(size_t)(i - 524288) * 4];
    const float4 v = *(const float4*)src;
    ushort4 o;
    o.x = f2bf(v.x); o.y = f2bf(v.y); o.z = f2bf(v.z); o.w = f2bf(v.w);
    *(ushort4*)&dst[(size_t)i * 4] = o;
}

// ---------------------------------------------------------------------------
// W [k][n] fp32 -> Wt [n][k] bf16
// ---------------------------------------------------------------------------
__global__ __launch_bounds__(256) void wtrans(
    const float* __restrict__ W0, const float* __restrict__ W1, const float* __restrict__ W2,
    unsigned short* __restrict__ T0, unsigned short* __restrict__ T1, unsigned short* __restrict__ T2)
{
    const float* __restrict__ W = blockIdx.z == 0 ? W0 : blockIdx.z == 1 ? W1 : W2;
    unsigned short* __restrict__ T = blockIdx.z == 0 ? T0 : blockIdx.z == 1 ? T1 : T2;
    __shared__ float tile[32][33];
    const int t = threadIdx.x;
    const int n0 = blockIdx.x * 32, k0 = blockIdx.y * 32;
    const int r = t >> 3, c4 = (t & 7) * 4;
    const float4 v = *(const float4*)&W[(size_t)(k0 + r) * DIM_ + n0 + c4];
    tile[r][c4 + 0] = v.x; tile[r][c4 + 1] = v.y; tile[r][c4 + 2] = v.z; tile[r][c4 + 3] = v.w;
    __syncthreads();
    ushort4 o;
    o.x = f2bf(tile[c4 + 0][r]); o.y = f2bf(tile[c4 + 1][r]);
    o.z = f2bf(tile[c4 + 2][r]); o.w = f2bf(tile[c4 + 3][r]);
    *(ushort4*)&T[(size_t)(n0 + r) * DIM_ + k0 + c4] = o;
}

// ---------------------------------------------------------------------------
// bf16 MFMA GEMM (B^T form), unchanged from rounds 2-4.
// ---------------------------------------------------------------------------
__global__ __launch_bounds__(256) void gemm_mfma_bt(
    const unsigned short* __restrict__ Ab,
    const unsigned short* __restrict__ Wt0, const unsigned short* __restrict__ Wt1, const unsigned short* __restrict__ Wt2,
    const float* __restrict__ b0, const float* __restrict__ b1, const float* __restrict__ b2,
    unsigned short* __restrict__ C0, unsigned short* __restrict__ C1, unsigned short* __restrict__ C2)
{
    const int z = blockIdx.z;
    const int m0 = blockIdx.y * 128, n0 = blockIdx.x * 128;
    if (z == 2 && m0 >= 2048) return;
    const unsigned short* __restrict__ Wt = z == 0 ? Wt0 : z == 1 ? Wt1 : Wt2;
    const float* __restrict__ bias        = z == 0 ? b0  : z == 1 ? b1  : b2;
    unsigned short* __restrict__ C        = z == 0 ? C0  : z == 1 ? C1  : C2;

    __shared__ unsigned short As[2][128 * 32];
    __shared__ unsigned short Bs[2][128 * 32];

    const int t = threadIdx.x, lane = t & 63, wave = t >> 6;
    const int wm = wave >> 1, wn = wave & 1;

    f32x4 acc[4][4];
#pragma unroll
    for (int i = 0; i < 4; ++i)
#pragma unroll
        for (int j = 0; j < 4; ++j) acc[i][j] = (f32x4){0.f, 0.f, 0.f, 0.f};

    const int c1 = wave * 64 + lane, c2 = c1 + 256;
    const int ar1 = c1 >> 2, ao1 = (c1 & 3) * 8;
    const int ar2 = c2 >> 2, ao2 = (c2 & 3) * 8;
    const int lr = lane & 15, lk = (lane >> 4) * 8;

#define STAGE(buf, kt) { \
    gload16(&Ab[(size_t)(m0 + ar1) * DIM_ + (kt) + ao1], &As[buf][c1 * 8]); \
    gload16(&Ab[(size_t)(m0 + ar2) * DIM_ + (kt) + ao2], &As[buf][c2 * 8]); \
    gload16(&Wt[(size_t)(n0 + ar1) * DIM_ + (kt) + ao1], &Bs[buf][c1 * 8]); \
    gload16(&Wt[(size_t)(n0 + ar2) * DIM_ + (kt) + ao2], &Bs[buf][c2 * 8]); }

    STAGE(0, 0)
    asm volatile("s_waitcnt vmcnt(0)" ::: "memory");
    __syncthreads();

    int cur = 0;
    for (int kt = 0; kt < DIM_; kt += 32) {
        if (kt + 32 < DIM_) STAGE(cur ^ 1, kt + 32)
        bf16x8 af[4], bfr[4];
#pragma unroll
        for (int i = 0; i < 4; ++i) {
            af[i]  = *(const bf16x8*)&As[cur][(wm * 64 + i * 16 + lr) * 32 + lk];
            bfr[i] = *(const bf16x8*)&Bs[cur][(wn * 64 + i * 16 + lr) * 32 + lk];
        }
#pragma unroll
        for (int i = 0; i < 4; ++i)
#pragma unroll
            for (int j = 0; j < 4; ++j)
                acc[i][j] = __builtin_amdgcn_mfma_f32_16x16x32_bf16(af[i], bfr[j], acc[i][j], 0, 0, 0);
        asm volatile("s_waitcnt vmcnt(0)" ::: "memory");
        __syncthreads();
        cur ^= 1;
    }
#undef STAGE

    const int rb = (lane >> 4) * 4;
#pragma unroll
    for (int j = 0; j < 4; ++j) {
        const int col = n0 + wn * 64 + j * 16 + lr;
        const float bv = bias[col];
#pragma unroll
        for (int i = 0; i < 4; ++i) {
            const int row = m0 + wm * 64 + i * 16 + rb;
#pragma unroll
            for (int r = 0; r < 4; ++r)
                C[(size_t)(row + r) * DIM_ + col] = f2bf(acc[i][j][r] + bv);
        }
    }
}

// ---------------------------------------------------------------------------
// V [b,s,h,d] bf16 -> Vt [b,h,d,k] bf16 (per (b,h): 64x512 transposed)
// ---------------------------------------------------------------------------
__global__ __launch_bounds__(256) void vtrans(const unsigned short* __restrict__ V,
                                              unsigned short* __restrict__ Vt) {
    const int t = threadIdx.x;
    const int k0 = blockIdx.x * 64;
    const int bh = blockIdx.y;
    const int b = bh >> 4, h = bh & 15;
    __shared__ unsigned short tl[64 * 72];
#pragma unroll
    for (int p = 0; p < 2; ++p) {
        const int idx = t + p * 256;
        const int r = idx >> 3, c8 = (idx & 7) * 8;
        const uint4 v = *(const uint4*)&V[((size_t)b * S_ + k0 + r) * DIM_ + h * HD_ + c8];
        *(uint4*)&tl[r * 72 + c8] = v;
    }
    __syncthreads();
#pragma unroll
    for (int p = 0; p < 2; ++p) {
        const int idx = t + p * 256;
        const int d = idx >> 3, k8 = (idx & 7) * 8;
        unsigned short tmp[8];
#pragma unroll
        for (int j = 0; j < 8; ++j) tmp[j] = tl[(k8 + j) * 72 + d];
        *(uint4*)&Vt[((size_t)bh * HD_ + d) * S_ + k0 + k8] = *(uint4*)tmp;
    }
}

// ---------------------------------------------------------------------------
// fused_attn v2: per (bh, q-tile 64) flash attention with banded rel-pos bias.
// All MFMA operands (K rows, PK/PQ band rows, Vt rows) come directly from
// global (L2-resident per bh; grid swizzled so one bh's q-blocks share an XCD).
// LDS only for the cross-lane diagonal scatters (SbG/SbH) and P. 2 barriers/tile.
// ---------------------------------------------------------------------------
__global__ __launch_bounds__(256) void fused_attn(
    const unsigned short* __restrict__ Q, const unsigned short* __restrict__ K,
    const unsigned short* __restrict__ Vt,
    const unsigned short* __restrict__ PK, const unsigned short* __restrict__ PQ,
    float* __restrict__ out)
{
    const int t = threadIdx.x, lane = t & 63, wave = t >> 6;
    const int lr = lane & 15, lg = lane >> 4;
    const int bh = blockIdx.x;            // 0..63  (consecutive ids share XCD per bh)
    const int q0 = blockIdx.y * 64;       // 0..448
    const int b = bh >> 4, h = bh & 15;
    const size_t base  = (size_t)b * S_ * DIM_ + h * HD_;
    const size_t vbase = (size_t)bh * HD_ * S_;

    __shared__ float SbG[64 * 65];        // bias c2p tile
    __shared__ float SbH[64 * 65];        // bias p2c tile
    __shared__ unsigned short P_lds[64 * 72];

    bf16x8 af_q[2];
    {
        const int qrow = q0 + wave * 16 + lr;
        af_q[0] = *(const bf16x8*)&Q[base + (size_t)qrow * DIM_ + lg * 8];
        af_q[1] = *(const bf16x8*)&Q[base + (size_t)qrow * DIM_ + 32 + lg * 8];
    }

    f32x4 O_acc[4];
#pragma unroll
    for (int df = 0; df < 4; ++df) O_acc[df] = (f32x4){0.f, 0.f, 0.f, 0.f};
    float m_run[4], l_run[4];
#pragma unroll
    for (int r = 0; r < 4; ++r) { m_run[r] = -1e30f; l_run[r] = 0.f; }

    const int lqr = wave * 16 + lg * 4;   // this thread's 4 q/k rows: lqr+reg

    for (int k0 = 0; k0 < S_; k0 += 64) {
        const int rbG = q0 - k0 + 448;    // PK band base (in [0,896], clip never binds)
        const int rbH = k0 - q0 + 448;    // PQ band base

        __syncthreads();   // Sb / P safe to overwrite (prev softmax+PV done)

        // S = Q @ K^T  (K rows direct from L2)
        f32x4 S_acc[4];
#pragma unroll
        for (int sf = 0; sf < 4; ++sf) S_acc[sf] = (f32x4){0.f, 0.f, 0.f, 0.f};
#pragma unroll
        for (int ks = 0; ks < 2; ++ks)
#pragma unroll
            for (int sf = 0; sf < 4; ++sf) {
                const bf16x8 bk = *(const bf16x8*)
                    &K[base + (size_t)(k0 + sf * 16 + lr) * DIM_ + ks * 32 + lg * 8];
                S_acc[sf] = __builtin_amdgcn_mfma_f32_16x16x32_bf16(af_q[ks], bk, S_acc[sf], 0, 0, 0);
            }

        // G = Q @ PKband^T (64x128), diagonal -> SbG (each cell exactly one writer)
        {
            f32x4 G[8];
#pragma unroll
            for (int rf = 0; rf < 8; ++rf) G[rf] = (f32x4){0.f, 0.f, 0.f, 0.f};
#pragma unroll
            for (int ks = 0; ks < 2; ++ks)
#pragma unroll
                for (int rf = 0; rf < 8; ++rf) {
                    const bf16x8 bp = *(const bf16x8*)
                        &PK[(size_t)(rbG + rf * 16 + lr) * DIM_ + h * HD_ + ks * 32 + lg * 8];
                    G[rf] = __builtin_amdgcn_mfma_f32_16x16x32_bf16(af_q[ks], bp, G[rf], 0, 0, 0);
                }
#pragma unroll
            for (int rf = 0; rf < 8; ++rf)
#pragma unroll
                for (int reg = 0; reg < 4; ++reg) {
                    const int lq = lqr + reg;
                    const int lk = lq + 63 - (rf * 16 + lr);
                    if ((unsigned)lk < 64u) SbG[lq * 65 + lk] = G[rf][reg];
                }
        }

        // H = K @ PQband^T (64x128), transposed diagonal -> SbH (plain writes)
        {
            bf16x8 af_k[2];
            const int krow = k0 + wave * 16 + lr;
            af_k[0] = *(const bf16x8*)&K[base + (size_t)krow * DIM_ + lg * 8];
            af_k[1] = *(const bf16x8*)&K[base + (size_t)krow * DIM_ + 32 + lg * 8];
            f32x4 Hf[8];
#pragma unroll
            for (int rf = 0; rf < 8; ++rf) Hf[rf] = (f32x4){0.f, 0.f, 0.f, 0.f};
#pragma unroll
            for (int ks = 0; ks < 2; ++ks)
#pragma unroll
                for (int rf = 0; rf < 8; ++rf) {
                    const bf16x8 bp = *(const bf16x8*)
                        &PQ[(size_t)(rbH + rf * 16 + lr) * DIM_ + h * HD_ + ks * 32 + lg * 8];
                    Hf[rf] = __builtin_amdgcn_mfma_f32_16x16x32_bf16(af_k[ks], bp, Hf[rf], 0, 0, 0);
                }
#pragma unroll
            for (int rf = 0; rf < 8; ++rf)
#pragma unroll
                for (int reg = 0; reg < 4; ++reg) {
                    const int lk = lqr + reg;
                    const int lq = lk + 63 - (rf * 16 + lr);
                    if ((unsigned)lq < 64u) SbH[lq * 65 + lk] = Hf[rf][reg];
                }
        }
        __syncthreads();   // scatters visible

        // scores + online softmax
        float sv[16];
#pragma unroll
        for (int sf = 0; sf < 4; ++sf)
#pragma unroll
            for (int reg = 0; reg < 4; ++reg) {
                const int idx = (lqr + reg) * 65 + sf * 16 + lr;
                sv[sf * 4 + reg] = (S_acc[sf][reg] + SbG[idx] + SbH[idx]) * SCORE_SCALE_;
            }

        float mt[4];
#pragma unroll
        for (int reg = 0; reg < 4; ++reg)
            mt[reg] = fmaxf(fmaxf(sv[reg], sv[4 + reg]), fmaxf(sv[8 + reg], sv[12 + reg]));
#pragma unroll
        for (int off = 8; off >= 1; off >>= 1)
#pragma unroll
            for (int reg = 0; reg < 4; ++reg)
                mt[reg] = fmaxf(mt[reg], __shfl_xor(mt[reg], off));

        float al[4], rs[4];
#pragma unroll
        for (int reg = 0; reg < 4; ++reg) {
            const float mn = fmaxf(m_run[reg], mt[reg]);
            al[reg] = __expf(m_run[reg] - mn);
            m_run[reg] = mn;
            rs[reg] = 0.f;
        }
        unsigned short pb[16];
#pragma unroll
        for (int sf = 0; sf < 4; ++sf)
#pragma unroll
            for (int reg = 0; reg < 4; ++reg) {
                const float p = __expf(sv[sf * 4 + reg] - m_run[reg]);
                const unsigned short pr = f2bf(p);
                pb[sf * 4 + reg] = pr;
                rs[reg] += bfs(pr);   // denominator consistent with bf16 P
            }
#pragma unroll
        for (int off = 8; off >= 1; off >>= 1)
#pragma unroll
            for (int reg = 0; reg < 4; ++reg)
                rs[reg] += __shfl_xor(rs[reg], off);
#pragma unroll
        for (int reg = 0; reg < 4; ++reg)
            l_run[reg] = l_run[reg] * al[reg] + rs[reg];
#pragma unroll
        for (int df = 0; df < 4; ++df)
#pragma unroll
            for (int reg = 0; reg < 4; ++reg)
                O_acc[df][reg] *= al[reg];

        // P into dedicated P_lds (own wave's rows; same-wave RAW via lgkmcnt)
#pragma unroll
        for (int sf = 0; sf < 4; ++sf)
#pragma unroll
            for (int reg = 0; reg < 4; ++reg)
                P_lds[(lqr + reg) * 72 + sf * 16 + lr] = pb[sf * 4 + reg];

        // O += P @ V  (Vt rows direct from L2)
#pragma unroll
        for (int ks = 0; ks < 2; ++ks) {
            const bf16x8 ap = *(const bf16x8*)&P_lds[(wave * 16 + lr) * 72 + ks * 32 + lg * 8];
#pragma unroll
            for (int df = 0; df < 4; ++df) {
                const bf16x8 bv = *(const bf16x8*)
                    &Vt[vbase + (size_t)(df * 16 + lr) * S_ + k0 + ks * 32 + lg * 8];
                O_acc[df] = __builtin_amdgcn_mfma_f32_16x16x32_bf16(ap, bv, O_acc[df], 0, 0, 0);
            }
        }
    }

#pragma unroll
    for (int df = 0; df < 4; ++df)
#pragma unroll
        for (int reg = 0; reg < 4; ++reg)
            out[((size_t)b * S_ + q0 + wave * 16 + lg * 4 + reg) * DIM_ +
                h * HD_ + df * 16 + lr] = O_acc[df][reg] / l_run[reg];
}

// ---------------------------------------------------------------------------
extern "C" void kernel_launch(void* const* d_in, const int* in_sizes, int n_in,
                              void* d_out, int out_size, void* d_ws, size_t ws_size,
                              hipStream_t stream) {
    (void)in_sizes; (void)n_in; (void)out_size; (void)ws_size;
    const float* x   = (const float*)d_in[0];
    const float* rel = (const float*)d_in[1];
    const float* Wq  = (const float*)d_in[2];
    const float* bq  = (const float*)d_in[3];
    const float* Wk  = (const float*)d_in[4];
    const float* bk  = (const float*)d_in[5];
    const float* Wv  = (const float*)d_in[6];
    const float* bv  = (const float*)d_in[7];
    float* out = (float*)d_out;

    unsigned short* Ab  = (unsigned short*)d_ws;      // [x(2048); rel(1024)] x 1024
    unsigned short* Wtq = Ab  + (size_t)3072 * 1024;
    unsigned short* Wtk = Wtq + (size_t)1024 * 1024;
    unsigned short* Wtv = Wtk + (size_t)1024 * 1024;
    unsigned short* Cq  = Wtv + (size_t)1024 * 1024;  // Q(2048 rows) | PQ(1024 rows)
    unsigned short* Ck  = Cq  + (size_t)3072 * 1024;  // K | PK
    unsigned short* Cv  = Ck  + (size_t)3072 * 1024;  // V (2048 rows)
    unsigned short* Vtb = Cv  + (size_t)2048 * 1024;  // Vt [bh][64][512]

    cvt2_bf16<<<3072, 256, 0, stream>>>(x, rel, Ab);
    wtrans<<<dim3(32, 32, 3), 256, 0, stream>>>(Wq, Wk, Wv, Wtq, Wtk, Wtv);
    gemm_mfma_bt<<<dim3(8, 24, 3), 256, 0, stream>>>(Ab, Wtq, Wtk, Wtv, bq, bk, bv, Cq, Ck, Cv);
    vtrans<<<dim3(8, 64), 256, 0, stream>>>(Cv, Vtb);

    const unsigned short* PKp = Ck + (size_t)2048 * 1024;   // rel @ Wk
    const unsigned short* PQp = Cq + (size_t)2048 * 1024;   // rel @ Wq

    fused_attn<<<dim3(64, 8), 256, 0, stream>>>(Cq, Ck, Vtb, PKp, PQp, out);
}

// Round 9
// 81.051 us; speedup vs baseline: 2.0274x; 2.0274x over previous
//
#include <hip/hip_runtime.h>
#include <math.h>

#define DIM_ 1024
#define B_ 4
#define S_ 512
#define H_ 16
#define HD_ 64
#define SCORE_SCALE_ 0.07216878364870323f

typedef __attribute__((ext_vector_type(8))) short bf16x8;
typedef __attribute__((ext_vector_type(4))) float f32x4;

__device__ __forceinline__ unsigned short f2bf(float f) {
    unsigned int u = __float_as_uint(f);
    u = u + 0x7fffu + ((u >> 16) & 1u);   // RNE (no NaN in data)
    return (unsigned short)(u >> 16);
}
__device__ __forceinline__ float bfs(unsigned short s) { return __uint_as_float(((unsigned int)s) << 16); }

__device__ __forceinline__ void gload16(const void* g, void* l) {
    __builtin_amdgcn_global_load_lds((const __attribute__((address_space(1))) void*)g,
                                     (__attribute__((address_space(3))) void*)l, 16, 0, 0);
}

// ---------------------------------------------------------------------------
// fp32 -> bf16 for x (first 524288 float4) and rel (next 262144), one launch
// ---------------------------------------------------------------------------
__global__ __launch_bounds__(256) void cvt2_bf16(const float* __restrict__ x,
                                                 const float* __restrict__ rel,
                                                 unsigned short* __restrict__ dst) {
    const int i = blockIdx.x * 256 + threadIdx.x;        // 0 .. 786431
    const float* src = (i < 524288) ? &x[(size_t)i * 4]
                                    : &rel[(size_t)(i - 524288) * 4];
    const float4 v = *(const float4*)src;
    ushort4 o;
    o.x = f2bf(v.x); o.y = f2bf(v.y); o.z = f2bf(v.z); o.w = f2bf(v.w);
    *(ushort4*)&dst[(size_t)i * 4] = o;
}

// ---------------------------------------------------------------------------
// W [k][n] fp32 -> Wt [n][k] bf16
// ---------------------------------------------------------------------------
__global__ __launch_bounds__(256) void wtrans(
    const float* __restrict__ W0, const float* __restrict__ W1, const float* __restrict__ W2,
    unsigned short* __restrict__ T0, unsigned short* __restrict__ T1, unsigned short* __restrict__ T2)
{
    const float* __restrict__ W = blockIdx.z == 0 ? W0 : blockIdx.z == 1 ? W1 : W2;
    unsigned short* __restrict__ T = blockIdx.z == 0 ? T0 : blockIdx.z == 1 ? T1 : T2;
    __shared__ float tile[32][33];
    const int t = threadIdx.x;
    const int n0 = blockIdx.x * 32, k0 = blockIdx.y * 32;
    const int r = t >> 3, c4 = (t & 7) * 4;
    const float4 v = *(const float4*)&W[(size_t)(k0 + r) * DIM_ + n0 + c4];
    tile[r][c4 + 0] = v.x; tile[r][c4 + 1] = v.y; tile[r][c4 + 2] = v.z; tile[r][c4 + 3] = v.w;
    __syncthreads();
    ushort4 o;
    o.x = f2bf(tile[c4 + 0][r]); o.y = f2bf(tile[c4 + 1][r]);
    o.z = f2bf(tile[c4 + 2][r]); o.w = f2bf(tile[c4 + 3][r]);
    *(ushort4*)&T[(size_t)(n0 + r) * DIM_ + k0 + c4] = o;
}

// ---------------------------------------------------------------------------
// bf16 MFMA GEMM (B^T form). z==0 output ([Q; pos_q]) is pre-scaled by
// SCORE_SCALE so the attention kernel adds raw S+G+H with no multiply.
// ---------------------------------------------------------------------------
__global__ __launch_bounds__(256) void gemm_mfma_bt(
    const unsigned short* __restrict__ Ab,
    const unsigned short* __restrict__ Wt0, const unsigned short* __restrict__ Wt1, const unsigned short* __restrict__ Wt2,
    const float* __restrict__ b0, const float* __restrict__ b1, const float* __restrict__ b2,
    unsigned short* __restrict__ C0, unsigned short* __restrict__ C1, unsigned short* __restrict__ C2)
{
    const int z = blockIdx.z;
    const int m0 = blockIdx.y * 128, n0 = blockIdx.x * 128;
    if (z == 2 && m0 >= 2048) return;
    const unsigned short* __restrict__ Wt = z == 0 ? Wt0 : z == 1 ? Wt1 : Wt2;
    const float* __restrict__ bias        = z == 0 ? b0  : z == 1 ? b1  : b2;
    unsigned short* __restrict__ C        = z == 0 ? C0  : z == 1 ? C1  : C2;
    const float scl = (z == 0) ? SCORE_SCALE_ : 1.0f;

    __shared__ unsigned short As[2][128 * 32];
    __shared__ unsigned short Bs[2][128 * 32];

    const int t = threadIdx.x, lane = t & 63, wave = t >> 6;
    const int wm = wave >> 1, wn = wave & 1;

    f32x4 acc[4][4];
#pragma unroll
    for (int i = 0; i < 4; ++i)
#pragma unroll
        for (int j = 0; j < 4; ++j) acc[i][j] = (f32x4){0.f, 0.f, 0.f, 0.f};

    const int c1 = wave * 64 + lane, c2 = c1 + 256;
    const int ar1 = c1 >> 2, ao1 = (c1 & 3) * 8;
    const int ar2 = c2 >> 2, ao2 = (c2 & 3) * 8;
    const int lr = lane & 15, lk = (lane >> 4) * 8;

#define STAGE(buf, kt) { \
    gload16(&Ab[(size_t)(m0 + ar1) * DIM_ + (kt) + ao1], &As[buf][c1 * 8]); \
    gload16(&Ab[(size_t)(m0 + ar2) * DIM_ + (kt) + ao2], &As[buf][c2 * 8]); \
    gload16(&Wt[(size_t)(n0 + ar1) * DIM_ + (kt) + ao1], &Bs[buf][c1 * 8]); \
    gload16(&Wt[(size_t)(n0 + ar2) * DIM_ + (kt) + ao2], &Bs[buf][c2 * 8]); }

    STAGE(0, 0)
    asm volatile("s_waitcnt vmcnt(0)" ::: "memory");
    __syncthreads();

    int cur = 0;
    for (int kt = 0; kt < DIM_; kt += 32) {
        if (kt + 32 < DIM_) STAGE(cur ^ 1, kt + 32)
        bf16x8 af[4], bfr[4];
#pragma unroll
        for (int i = 0; i < 4; ++i) {
            af[i]  = *(const bf16x8*)&As[cur][(wm * 64 + i * 16 + lr) * 32 + lk];
            bfr[i] = *(const bf16x8*)&Bs[cur][(wn * 64 + i * 16 + lr) * 32 + lk];
        }
#pragma unroll
        for (int i = 0; i < 4; ++i)
#pragma unroll
            for (int j = 0; j < 4; ++j)
                acc[i][j] = __builtin_amdgcn_mfma_f32_16x16x32_bf16(af[i], bfr[j], acc[i][j], 0, 0, 0);
        asm volatile("s_waitcnt vmcnt(0)" ::: "memory");
        __syncthreads();
        cur ^= 1;
    }
#undef STAGE

    const int rb = (lane >> 4) * 4;
#pragma unroll
    for (int j = 0; j < 4; ++j) {
        const int col = n0 + wn * 64 + j * 16 + lr;
        const float bv = bias[col];
#pragma unroll
        for (int i = 0; i < 4; ++i) {
            const int row = m0 + wm * 64 + i * 16 + rb;
#pragma unroll
            for (int r = 0; r < 4; ++r)
                C[(size_t)(row + r) * DIM_ + col] = f2bf((acc[i][j][r] + bv) * scl);
        }
    }
}

// ---------------------------------------------------------------------------
// V [b,s,h,d] bf16 -> Vt [bh,d,k] bf16
// ---------------------------------------------------------------------------
__global__ __launch_bounds__(256) void vtrans(const unsigned short* __restrict__ V,
                                              unsigned short* __restrict__ Vt) {
    const int t = threadIdx.x;
    const int k0 = blockIdx.x * 64;
    const int bh = blockIdx.y;
    const int b = bh >> 4, h = bh & 15;
    __shared__ unsigned short tl[64 * 72];
#pragma unroll
    for (int p = 0; p < 2; ++p) {
        const int idx = t + p * 256;
        const int r = idx >> 3, c8 = (idx & 7) * 8;
        const uint4 v = *(const uint4*)&V[((size_t)b * S_ + k0 + r) * DIM_ + h * HD_ + c8];
        *(uint4*)&tl[r * 72 + c8] = v;
    }
    __syncthreads();
#pragma unroll
    for (int p = 0; p < 2; ++p) {
        const int idx = t + p * 256;
        const int d = idx >> 3, k8 = (idx & 7) * 8;
        unsigned short tmp[8];
#pragma unroll
        for (int j = 0; j < 8; ++j) tmp[j] = tl[(k8 + j) * 72 + d];
        *(uint4*)&Vt[((size_t)bh * HD_ + d) * S_ + k0 + k8] = *(uint4*)tmp;
    }
}

// ---------------------------------------------------------------------------
// fused_attn v3: per (bh, q-tile 64) flash attention with banded rel-pos bias.
//  - K / PK-band / PQ-band staged to LDS via global_load_lds DMA with
//    XOR-swizzled SOURCE addressing (linear LDS dest); reads apply the same
//    chunk^(row&7) XOR -> conflict-free ds_read_b128, zero staging VALU.
//  - Band trick: per wave only col-frags rf = w..w+4 of G/H intersect the
//    diagonal -> 10 MFMAs each instead of 16.
//  - Vt fragments prefetched into registers after bar3 (hidden under softmax).
//  - Q and pos_q pre-scaled by SCORE_SCALE in the GEMM; sv = S + Sb directly.
// 3 barriers / k-tile; LDS 65.3 KB -> 2 blocks/CU.
// ---------------------------------------------------------------------------
__global__ __launch_bounds__(256) void fused_attn(
    const unsigned short* __restrict__ Q, const unsigned short* __restrict__ K,
    const unsigned short* __restrict__ Vt,
    const unsigned short* __restrict__ PK, const unsigned short* __restrict__ PQ,
    float* __restrict__ out)
{
    const int t = threadIdx.x, lane = t & 63, wave = t >> 6;
    const int lr = lane & 15, lg = lane >> 4;
    const int bh = blockIdx.x;            // id = bh + 64*qt -> same bh shares XCD
    const int q0 = blockIdx.y * 64;
    const int b = bh >> 4, h = bh & 15;
    const size_t base  = (size_t)b * S_ * DIM_ + h * HD_;
    const size_t vbase = (size_t)bh * HD_ * S_;

    __shared__ unsigned short K_lds[64 * 64];     // 8 KB, linear (DMA dest)
    __shared__ unsigned short PK_lds[128 * 64];   // 16 KB
    __shared__ unsigned short PQ_lds[128 * 64];   // 16 KB
    __shared__ float Sb[64 * 65];                 // 16.6 KB bias tile
    __shared__ unsigned short P_lds[64 * 72];     // 9.2 KB

    auto stage_tile = [&](int kn) {
        const int rbG_ = q0 - kn + 448;           // PK band base (clip never binds)
        const int rbH_ = kn - q0 + 448;           // PQ band base
#pragma unroll
        for (int p = 0; p < 2; ++p) {
            const int c = wave * 64 + lane + p * 256, r = c >> 3;
            const int jc = (c & 7) ^ (r & 7);     // source-side XOR swizzle
            gload16(&K[base + (size_t)(kn + r) * DIM_ + jc * 8], &K_lds[(size_t)c * 8]);
        }
#pragma unroll
        for (int p = 0; p < 4; ++p) {
            const int c = wave * 64 + lane + p * 256, r = c >> 3;
            const int jc = (c & 7) ^ (r & 7);
            gload16(&PK[(size_t)(rbG_ + r) * DIM_ + h * HD_ + jc * 8], &PK_lds[(size_t)c * 8]);
            gload16(&PQ[(size_t)(rbH_ + r) * DIM_ + h * HD_ + jc * 8], &PQ_lds[(size_t)c * 8]);
        }
    };

    bf16x8 af_q[2];
    {
        const int qrow = q0 + wave * 16 + lr;
        af_q[0] = *(const bf16x8*)&Q[base + (size_t)qrow * DIM_ + lg * 8];
        af_q[1] = *(const bf16x8*)&Q[base + (size_t)qrow * DIM_ + 32 + lg * 8];
    }

    f32x4 O_acc[4];
#pragma unroll
    for (int df = 0; df < 4; ++df) O_acc[df] = (f32x4){0.f, 0.f, 0.f, 0.f};
    float m_run[4], l_run[4];
#pragma unroll
    for (int r = 0; r < 4; ++r) { m_run[r] = -1e30f; l_run[r] = 0.f; }

    const int lqr = wave * 16 + lg * 4;      // this thread's 4 rows: lqr+reg
    const int swz = lr & 7;
    const int dbase = lg * 4 + 63 - lr;      // diag index base

    stage_tile(0);

    for (int k0 = 0; k0 < S_; k0 += 64) {
        asm volatile("s_waitcnt vmcnt(0)" ::: "memory");
        __syncthreads();                     // staged tiles visible

        // S = Q @ K^T
        f32x4 S_acc[4];
#pragma unroll
        for (int sf = 0; sf < 4; ++sf) S_acc[sf] = (f32x4){0.f, 0.f, 0.f, 0.f};
#pragma unroll
        for (int ks = 0; ks < 2; ++ks)
#pragma unroll
            for (int sf = 0; sf < 4; ++sf) {
                const bf16x8 bk = *(const bf16x8*)
                    &K_lds[(size_t)(sf * 16 + lr) * 64 + (((ks * 4 + lg) ^ swz) * 8)];
                S_acc[sf] = __builtin_amdgcn_mfma_f32_16x16x32_bf16(af_q[ks], bk, S_acc[sf], 0, 0, 0);
            }

        // G = Q @ PKband^T, only the 5 col-frags that touch the diagonal
        f32x4 G[5];
#pragma unroll
        for (int c = 0; c < 5; ++c) G[c] = (f32x4){0.f, 0.f, 0.f, 0.f};
#pragma unroll
        for (int ks = 0; ks < 2; ++ks)
#pragma unroll
            for (int c = 0; c < 5; ++c) {
                const bf16x8 bp = *(const bf16x8*)
                    &PK_lds[(size_t)((wave + c) * 16 + lr) * 64 + (((ks * 4 + lg) ^ swz) * 8)];
                G[c] = __builtin_amdgcn_mfma_f32_16x16x32_bf16(af_q[ks], bp, G[c], 0, 0, 0);
            }

        // H = K @ PQband^T, same 5 frags
        bf16x8 af_k[2];
#pragma unroll
        for (int ks = 0; ks < 2; ++ks)
            af_k[ks] = *(const bf16x8*)
                &K_lds[(size_t)(wave * 16 + lr) * 64 + (((ks * 4 + lg) ^ swz) * 8)];
        f32x4 Hf[5];
#pragma unroll
        for (int c = 0; c < 5; ++c) Hf[c] = (f32x4){0.f, 0.f, 0.f, 0.f};
#pragma unroll
        for (int ks = 0; ks < 2; ++ks)
#pragma unroll
            for (int c = 0; c < 5; ++c) {
                const bf16x8 bp = *(const bf16x8*)
                    &PQ_lds[(size_t)((wave + c) * 16 + lr) * 64 + (((ks * 4 + lg) ^ swz) * 8)];
                Hf[c] = __builtin_amdgcn_mfma_f32_16x16x32_bf16(af_k[ks], bp, Hf[c], 0, 0, 0);
            }

        // G diagonal scatter (each cell has exactly one writer)
#pragma unroll
        for (int c = 0; c < 5; ++c)
#pragma unroll
            for (int reg = 0; reg < 4; ++reg) {
                const int lk = dbase + reg - 16 * c;
                if ((unsigned)lk < 64u) Sb[(lqr + reg) * 65 + lk] = G[c][reg];
            }
        __syncthreads();                     // G writes done before H RMW

        // H transposed-diagonal accumulate
#pragma unroll
        for (int c = 0; c < 5; ++c)
#pragma unroll
            for (int reg = 0; reg < 4; ++reg) {
                const int lq = dbase + reg - 16 * c;
                if ((unsigned)lq < 64u) Sb[lq * 65 + lqr + reg] += Hf[c][reg];
            }
        __syncthreads();                     // Sb final

        // Vt fragment prefetch for PV (regs; latency hides under softmax)
        bf16x8 vt[8];
#pragma unroll
        for (int ks = 0; ks < 2; ++ks)
#pragma unroll
            for (int df = 0; df < 4; ++df)
                vt[ks * 4 + df] = *(const bf16x8*)
                    &Vt[vbase + (size_t)(df * 16 + lr) * S_ + k0 + ks * 32 + lg * 8];

        // scores (pre-scaled) + online softmax
        float sv[16];
#pragma unroll
        for (int sf = 0; sf < 4; ++sf)
#pragma unroll
            for (int reg = 0; reg < 4; ++reg)
                sv[sf * 4 + reg] = S_acc[sf][reg] + Sb[(lqr + reg) * 65 + sf * 16 + lr];

        float mt[4];
#pragma unroll
        for (int reg = 0; reg < 4; ++reg)
            mt[reg] = fmaxf(fmaxf(sv[reg], sv[4 + reg]), fmaxf(sv[8 + reg], sv[12 + reg]));
#pragma unroll
        for (int off = 8; off >= 1; off >>= 1)
#pragma unroll
            for (int reg = 0; reg < 4; ++reg)
                mt[reg] = fmaxf(mt[reg], __shfl_xor(mt[reg], off));

        float al[4], rs[4];
#pragma unroll
        for (int reg = 0; reg < 4; ++reg) {
            const float mn = fmaxf(m_run[reg], mt[reg]);
            al[reg] = __expf(m_run[reg] - mn);
            m_run[reg] = mn;
            rs[reg] = 0.f;
        }
        unsigned short pb[16];
#pragma unroll
        for (int sf = 0; sf < 4; ++sf)
#pragma unroll
            for (int reg = 0; reg < 4; ++reg) {
                const float p = __expf(sv[sf * 4 + reg] - m_run[reg]);
                const unsigned short pr = f2bf(p);
                pb[sf * 4 + reg] = pr;
                rs[reg] += bfs(pr);          // denominator consistent with bf16 P
            }
#pragma unroll
        for (int off = 8; off >= 1; off >>= 1)
#pragma unroll
            for (int reg = 0; reg < 4; ++reg)
                rs[reg] += __shfl_xor(rs[reg], off);
#pragma unroll
        for (int reg = 0; reg < 4; ++reg)
            l_run[reg] = l_run[reg] * al[reg] + rs[reg];
#pragma unroll
        for (int df = 0; df < 4; ++df)
#pragma unroll
            for (int reg = 0; reg < 4; ++reg)
                O_acc[df][reg] *= al[reg];

        // P into P_lds (own wave's rows; same-wave RAW via lgkmcnt)
#pragma unroll
        for (int sf = 0; sf < 4; ++sf)
#pragma unroll
            for (int reg = 0; reg < 4; ++reg)
                P_lds[(lqr + reg) * 72 + sf * 16 + lr] = pb[sf * 4 + reg];

        // O += P @ V (B-fragments from registers)
#pragma unroll
        for (int ks = 0; ks < 2; ++ks) {
            const bf16x8 ap = *(const bf16x8*)&P_lds[(wave * 16 + lr) * 72 + ks * 32 + lg * 8];
#pragma unroll
            for (int df = 0; df < 4; ++df)
                O_acc[df] = __builtin_amdgcn_mfma_f32_16x16x32_bf16(ap, vt[ks * 4 + df], O_acc[df], 0, 0, 0);
        }

        // issue next tile's DMA (all waves past bar3 -> staged regions dead)
        if (k0 + 64 < S_) stage_tile(k0 + 64);
    }

#pragma unroll
    for (int df = 0; df < 4; ++df)
#pragma unroll
        for (int reg = 0; reg < 4; ++reg)
            out[((size_t)b * S_ + q0 + wave * 16 + lg * 4 + reg) * DIM_ +
                h * HD_ + df * 16 + lr] = O_acc[df][reg] / l_run[reg];
}

// ---------------------------------------------------------------------------
extern "C" void kernel_launch(void* const* d_in, const int* in_sizes, int n_in,
                              void* d_out, int out_size, void* d_ws, size_t ws_size,
                              hipStream_t stream) {
    (void)in_sizes; (void)n_in; (void)out_size; (void)ws_size;
    const float* x   = (const float*)d_in[0];
    const float* rel = (const float*)d_in[1];
    const float* Wq  = (const float*)d_in[2];
    const float* bq  = (const float*)d_in[3];
    const float* Wk  = (const float*)d_in[4];
    const float* bk  = (const float*)d_in[5];
    const float* Wv  = (const float*)d_in[6];
    const float* bv  = (const float*)d_in[7];
    float* out = (float*)d_out;

    unsigned short* Ab  = (unsigned short*)d_ws;      // [x(2048); rel(1024)] x 1024
    unsigned short* Wtq = Ab  + (size_t)3072 * 1024;
    unsigned short* Wtk = Wtq + (size_t)1024 * 1024;
    unsigned short* Wtv = Wtk + (size_t)1024 * 1024;
    unsigned short* Cq  = Wtv + (size_t)1024 * 1024;  // Q(2048) | pos_q(1024), pre-scaled
    unsigned short* Ck  = Cq  + (size_t)3072 * 1024;  // K | pos_k
    unsigned short* Cv  = Ck  + (size_t)3072 * 1024;  // V (2048)
    unsigned short* Vtb = Cv  + (size_t)2048 * 1024;  // Vt [bh][64][512]

    cvt2_bf16<<<3072, 256, 0, stream>>>(x, rel, Ab);
    wtrans<<<dim3(32, 32, 3), 256, 0, stream>>>(Wq, Wk, Wv, Wtq, Wtk, Wtv);
    gemm_mfma_bt<<<dim3(8, 24, 3), 256, 0, stream>>>(Ab, Wtq, Wtk, Wtv, bq, bk, bv, Cq, Ck, Cv);
    vtrans<<<dim3(8, 64), 256, 0, stream>>>(Cv, Vtb);

    const unsigned short* PKp = Ck + (size_t)2048 * 1024;   // rel @ Wk
    const unsigned short* PQp = Cq + (size_t)2048 * 1024;   // (rel @ Wq) * SCALE

    fused_attn<<<dim3(64, 8), 256, 0, stream>>>(Cq, Ck, Vtb, PKp, PQp, out);
}